// Round 1
// 214.729 us; speedup vs baseline: 1.0700x; 1.0700x over previous
//
#include <hip/hip_runtime.h>

#define SEQ 2048
#define NH 16
#define HD 64
#define DMODEL 1024

typedef short bf16x8 __attribute__((ext_vector_type(8)));
typedef float f32x16 __attribute__((ext_vector_type(16)));

union FragU {
    bf16x8 v;
    uint2 u2[2];
    unsigned int w[4];
    unsigned short s[8];
};

// Pack two f32 -> packed bf16 pair (lo in low 16 bits).
#if __has_builtin(__builtin_amdgcn_cvt_pk_bf16_f32)
typedef __bf16 v2bf_t __attribute__((ext_vector_type(2)));
__device__ __forceinline__ unsigned int pack_bf16(float lo, float hi) {
    union { v2bf_t h; unsigned int u; } cv;
    cv.h = __builtin_amdgcn_cvt_pk_bf16_f32(lo, hi);
    return cv.u;
}
#else
__device__ __forceinline__ unsigned int pack_bf16(float lo, float hi) {
    unsigned int a = __float_as_uint(lo) + 0x8000u;
    unsigned int b = __float_as_uint(hi) + 0x8000u;
    return __builtin_amdgcn_perm(b, a, 0x07060302);  // {b.hi16, a.hi16}
}
#endif

#define EXP_SCALE 1.44269504f   // 1/ln2, folded into Q and bias table
#define LN2       0.69314718f   // folded into epilogue store

// Block: 512 threads = 8 waves; each wave computes a 32q x 64d output tile
// (block covers 256 q for one (b,h)).
// Structure: double-buffered K/V LDS tiles, ONE barrier per k-tile.
// Per iter: issue global loads for tile t+1 right after the barrier (latency
// hides under compute), compute X^T = 1.4427*(K*Q^T + bias) with interleaved
// accumulator chains, silu in-register, pack+ds_write tile t+1 late (lands
// before the end-of-iter barrier), then O += P*V from the current buffer.
__global__ __launch_bounds__(512, 4)
void paa_kernel(const float* __restrict__ Vg, const float* __restrict__ Kg,
                const float* __restrict__ Qg, const float* __restrict__ RW,
                float* __restrict__ Og)
{
    __shared__ __align__(16) unsigned short KsLds[2][64 * 68];  // [kc][d], stride 68
    __shared__ __align__(16) unsigned short VtLds[2][64 * 68];  // [d][kc], stride 68
    __shared__ float btab[128];  // 1.4427*bias by distance, clamped at 127

    const int tid  = threadIdx.x;
    const int lane = tid & 63;
    const int wave = tid >> 6;   // 0..7
    const int half = lane >> 5;
    const int l31  = lane & 31;

    const int bid  = blockIdx.x;
    const int bh   = bid & 63;
    const int qt   = bid >> 6;   // 0..7
    const int b    = bh >> 4;
    const int head = bh & 15;

    const int q0w = qt * 256 + wave * 32;   // 32 q rows per wave

    // ---- bias table (pre-scaled by 1/ln2) ----
    if (tid < 128) {
        int rp = tid;
        int bucket;
        if (rp < 16) bucket = rp;
        else {
            int big = 16 + (int)(logf((float)rp * 0.0625f) * 7.6943736f); // 16/ln(8)
            bucket = big < 31 ? big : 31;
        }
        btab[tid] = RW[bucket * NH + head] * EXP_SCALE;
    }

    // ---- preload Q fragments (B operand of S^T), pre-scaled by 1/ln2 ----
    FragU qf[4];
    {
        const float* qrow = Qg + (size_t)(b * SEQ + q0w + l31) * DMODEL + head * HD;
        #pragma unroll
        for (int kf = 0; kf < 4; ++kf) {
            int dd = kf * 16 + half * 8;
            float4 x0 = *(const float4*)(qrow + dd);
            float4 x1 = *(const float4*)(qrow + dd + 4);
            FragU f;
            f.w[0] = pack_bf16(x0.x * EXP_SCALE, x0.y * EXP_SCALE);
            f.w[1] = pack_bf16(x0.z * EXP_SCALE, x0.w * EXP_SCALE);
            f.w[2] = pack_bf16(x1.x * EXP_SCALE, x1.y * EXP_SCALE);
            f.w[3] = pack_bf16(x1.z * EXP_SCALE, x1.w * EXP_SCALE);
            qf[kf] = f;
        }
    }

    f32x16 oacc[2];
    #pragma unroll
    for (int n = 0; n < 2; ++n)
        #pragma unroll
        for (int r = 0; r < 16; ++r) oacc[n][r] = 0.0f;

    // staging geometry (512 threads stage a 64x64 tile of K and of V)
    const int krow = tid >> 4;   // 0..31 (+32 for second half)
    const int c4   = tid & 15;
    const int kc2  = tid >> 4;   // V: 2 kc rows at kc2*2
    const int d4   = tid & 15;   // V: 4 d cols at d4*4

    const float* kp = Kg + (size_t)(b * SEQ + krow) * DMODEL + head * HD + c4 * 4;
    const float* vp = Vg + (size_t)(b * SEQ + kc2 * 2) * DMODEL + head * HD + d4 * 4;

    // ---- prologue: stage tile 0 into buffer 0 ----
    {
        float4 k0 = *(const float4*)(kp);
        float4 k1 = *(const float4*)(kp + (size_t)32 * DMODEL);
        float4 v0 = *(const float4*)(vp);
        float4 v1 = *(const float4*)(vp + DMODEL);
        kp += (size_t)64 * DMODEL;
        vp += (size_t)64 * DMODEL;
        uint2 w;
        w.x = pack_bf16(k0.x, k0.y); w.y = pack_bf16(k0.z, k0.w);
        *(uint2*)&KsLds[0][krow * 68 + c4 * 4] = w;
        w.x = pack_bf16(k1.x, k1.y); w.y = pack_bf16(k1.z, k1.w);
        *(uint2*)&KsLds[0][(krow + 32) * 68 + c4 * 4] = w;
        *(unsigned int*)&VtLds[0][(d4 * 4 + 0) * 68 + kc2 * 2] = pack_bf16(v0.x, v1.x);
        *(unsigned int*)&VtLds[0][(d4 * 4 + 1) * 68 + kc2 * 2] = pack_bf16(v0.y, v1.y);
        *(unsigned int*)&VtLds[0][(d4 * 4 + 2) * 68 + kc2 * 2] = pack_bf16(v0.z, v1.z);
        *(unsigned int*)&VtLds[0][(d4 * 4 + 3) * 68 + kc2 * 2] = pack_bf16(v0.w, v1.w);
    }
    __syncthreads();

    const float bias_d0  = btab[0];    // all d <= 0  -> bucket 0
    const float bias_far = btab[127];  // all d >= 113 -> bucket 31

    #pragma unroll 2
    for (int it = 0; it < 32; ++it) {
        const int cur = it & 1;
        const int kcb = it * 64;
        const unsigned short* Ks = KsLds[cur];
        const unsigned short* Vt = VtLds[cur];
        const bool pre = (it < 31);

        // ---- issue next-tile global loads EARLY (latency hides under compute) ----
        float4 k0, k1, v0, v1;
        if (pre) {
            k0 = *(const float4*)(kp);
            k1 = *(const float4*)(kp + (size_t)32 * DMODEL);
            v0 = *(const float4*)(vp);
            v1 = *(const float4*)(vp + DMODEL);
            kp += (size_t)64 * DMODEL;
            vp += (size_t)64 * DMODEL;
        }

        // ---- X^T = K * Q^T + bias (bias in accumulator init), two interleaved chains ----
        f32x16 st[2];
        #pragma unroll
        for (int t = 0; t < 2; ++t) {
            const int kcmin = kcb + t * 32;
            if (q0w + 31 - kcmin <= 0) {               // whole tile d<=0
                #pragma unroll
                for (int r = 0; r < 16; ++r) st[t][r] = bias_d0;
            } else if (q0w - (kcmin + 31) >= 113) {    // whole tile bucket 31
                #pragma unroll
                for (int r = 0; r < 16; ++r) st[t][r] = bias_far;
            } else {                                   // mixed band (~9% of tiles)
                const int dql = q0w + l31 - kcmin - 4 * half;
                #pragma unroll
                for (int r = 0; r < 16; ++r) {
                    int dv = dql - ((r & 3) + 8 * (r >> 2));
                    dv = dv < 0 ? 0 : (dv > 127 ? 127 : dv);
                    st[t][r] = btab[dv];
                }
            }
        }

        __builtin_amdgcn_s_setprio(1);
        #pragma unroll
        for (int kf = 0; kf < 4; ++kf) {
            FragU ka0, ka1;
            {
                int off = l31 * 68 + kf * 16 + half * 8;
                ka0.u2[0] = *(const uint2*)&Ks[off];
                ka0.u2[1] = *(const uint2*)&Ks[off + 4];
                off += 32 * 68;
                ka1.u2[0] = *(const uint2*)&Ks[off];
                ka1.u2[1] = *(const uint2*)&Ks[off + 4];
            }
            st[0] = __builtin_amdgcn_mfma_f32_32x32x16_bf16(ka0.v, qf[kf].v, st[0], 0, 0, 0);
            st[1] = __builtin_amdgcn_mfma_f32_32x32x16_bf16(ka1.v, qf[kf].v, st[1], 0, 0, 0);
        }
        __builtin_amdgcn_s_setprio(0);

        // ---- silu: p = x * rcp(1 + exp2(-x))  == 1.4427 * silu(x*ln2) ----
        FragU pf[4];
        #pragma unroll
        for (int t = 0; t < 2; ++t) {
            float vals[16];
            #pragma unroll
            for (int r = 0; r < 16; ++r) {
                float x = st[t][r];
                float e = __builtin_amdgcn_exp2f(-x);
                vals[r] = x * __builtin_amdgcn_rcpf(1.0f + e);
            }
            #pragma unroll
            for (int j = 0; j < 4; ++j)
                pf[t * 2].w[j]     = pack_bf16(vals[2 * j], vals[2 * j + 1]);
            #pragma unroll
            for (int j = 0; j < 4; ++j)
                pf[t * 2 + 1].w[j] = pack_bf16(vals[8 + 2 * j], vals[9 + 2 * j]);
        }

        // ---- pack + ds_write next tile into the other buffer (loads long done) ----
        if (pre) {
            const int nb = cur ^ 1;
            uint2 w;
            w.x = pack_bf16(k0.x, k0.y); w.y = pack_bf16(k0.z, k0.w);
            *(uint2*)&KsLds[nb][krow * 68 + c4 * 4] = w;
            w.x = pack_bf16(k1.x, k1.y); w.y = pack_bf16(k1.z, k1.w);
            *(uint2*)&KsLds[nb][(krow + 32) * 68 + c4 * 4] = w;
            *(unsigned int*)&VtLds[nb][(d4 * 4 + 0) * 68 + kc2 * 2] = pack_bf16(v0.x, v1.x);
            *(unsigned int*)&VtLds[nb][(d4 * 4 + 1) * 68 + kc2 * 2] = pack_bf16(v0.y, v1.y);
            *(unsigned int*)&VtLds[nb][(d4 * 4 + 2) * 68 + kc2 * 2] = pack_bf16(v0.z, v1.z);
            *(unsigned int*)&VtLds[nb][(d4 * 4 + 3) * 68 + kc2 * 2] = pack_bf16(v0.w, v1.w);
        }

        // ---- O += P * V : V B-fragments address-matched to P's k-slot permutation ----
        #pragma unroll
        for (int f = 0; f < 4; ++f) {
            #pragma unroll
            for (int n = 0; n < 2; ++n) {
                FragU vf;
                int off = (n * 32 + l31) * 68 + f * 16 + half * 4;
                vf.u2[0] = *(const uint2*)&Vt[off];      // kc offsets 4h..4h+3
                vf.u2[1] = *(const uint2*)&Vt[off + 8];  // kc offsets 4h+8..4h+11
                oacc[n] = __builtin_amdgcn_mfma_f32_32x32x16_bf16(pf[f].v, vf.v, oacc[n], 0, 0, 0);
            }
        }

        // ---- single barrier per iter: next buffer written, current reads done ----
        if (pre) __syncthreads();
    }

    // ---- store (x ln2): C layout row=q_local, col=d_local ----
    float* obase = Og + (size_t)(b * SEQ) * DMODEL + head * HD;
    #pragma unroll
    for (int r = 0; r < 16; ++r) {
        int q = q0w + (r & 3) + 8 * (r >> 2) + 4 * half;
        float* orow = obase + (size_t)q * DMODEL;
        #pragma unroll
        for (int n = 0; n < 2; ++n)
            orow[n * 32 + l31] = oacc[n][r] * LN2;
    }
}

extern "C" void kernel_launch(void* const* d_in, const int* in_sizes, int n_in,
                              void* d_out, int out_size, void* d_ws, size_t ws_size,
                              hipStream_t stream) {
    const float* v  = (const float*)d_in[0];
    const float* k  = (const float*)d_in[1];
    const float* q  = (const float*)d_in[2];
    const float* rw = (const float*)d_in[3];
    float* out = (float*)d_out;
    paa_kernel<<<dim3(512), dim3(512), 0, stream>>>(v, k, q, rw, out);
}